// Round 7
// baseline (173.286 us; speedup 1.0000x reference)
//
#include <hip/hip_runtime.h>
#include <math.h>

#define BB 128
#define TT 1024
#define NN 64
#define NCH 16              // chunks per batch
#define SCH 64              // steps per chunk

typedef __attribute__((ext_vector_type(4))) float f32x4;
typedef __attribute__((ext_vector_type(4))) short bf16x4;

__device__ __forceinline__ float wave_sum64(float v) {
#pragma unroll
  for (int o = 32; o > 0; o >>= 1) v += __shfl_xor(v, o, 64);
  return v;
}

// pack two positive f32 into a bf16-pair dword (round-half-up)
__device__ __forceinline__ unsigned pkbf(float lo, float hi) {
  unsigned a = __float_as_uint(lo) + 0x8000u;
  unsigned b = __float_as_uint(hi) + 0x8000u;
  return __builtin_amdgcn_perm(b, a, 0x07060302u);
}

__device__ __forceinline__ int fexp(float x) {  // unbiased exponent, 0 for denorm/zero
  unsigned u = __float_as_uint(x);
  int e = (int)((u >> 23) & 0xffu) - 127;
  if ((u & 0x7f800000u) == 0) e = 0;
  return e;
}

// ============================ PHASE 1 + SCORE =============================
// grid = 32 + 2048 blocks x 256 threads (4 independent waves, no barriers).
//  blk < 32 : sequence score; wave w handles batch blk*4+w.
//  blk >= 32: idx = blk-32; c = idx>>7 (high bits -> per-CU chunk balance),
//             b = idx&127; wave w = col-group g.
//    Wave evolves 16 cols [16g,16g+16) of H = diag(p_last)·[E^T diag(p)]···E^T
//    (bf16, scaled 2^-etot) in registers (16x16x16 MFMA: D layout == B layout).
//    px = exp(pot[t,:]) broadcast via per-wave LDS ring (same-wave DS order);
//    ring region is reused as the epilogue transpose buffer.
//    Out: Hg[(b*16+c)*2048 + (8g+w)*64 + j] = H[row j][cols 16g+2w, 16g+2w+1].
__global__ __launch_bounds__(256, 6) void crf_phase1(
    const float* __restrict__ pot, const int* __restrict__ tags,
    const int* __restrict__ seqlen, const float* __restrict__ K,
    unsigned* __restrict__ Hg, int* __restrict__ Eexp, float* __restrict__ score,
    float* __restrict__ accf, unsigned* __restrict__ cnt) {
  __shared__ __align__(16) unsigned char smem[4][2176];  // per-wave: ring(1KB)/transpose(2176B)
  const int tid = threadIdx.x;
  const int wv = tid >> 6;
  const int lane = tid & 63;
  const int blk = blockIdx.x;

  if (blk == 0 && tid == 0) { *accf = 0.0f; *cnt = 0u; }  // zero atomic slots

  if (blk < 32) {
    // ---------------- sequence score (K via L1/L2) ----------------
    const int b = blk * 4 + wv;
    const int L = seqlen[b];
    const int* tg = tags + b * TT;
    const float* pbase = pot + (size_t)b * TT * NN;
    float acc = 0.0f;
    for (int t = lane; t < TT; t += 64) {
      if (t < L) {
        int cc = tg[t];
        float u = pbase[(size_t)t * 64 + cc];
        float tr = (t >= 1) ? K[tg[t - 1] * 64 + cc] : 0.0f;
        acc += u + tr;
      }
    }
    acc = wave_sum64(acc);
    if (lane == 0) score[b] = acc;
    return;
  }

  const int idx = blk - 32;
  const int c = idx >> 7;            // chunk index in HIGH bits (per-CU balance)
  const int b = idx & (BB - 1);
  const int g = wv;                  // col-group 0..3
  const int L = seqlen[b];
  const int q = lane >> 4, lm = lane & 15;
  const int rb = q * 4;              // lane's base row within a 16-row k-tile

  const int t0 = c * SCH + 1;
  const int tend = (L < TT) ? L : TT;
  int nsteps = tend - t0;
  if (nsteps > SCH) nsteps = SCH;

  unsigned* Hc = Hg + (size_t)(b * NCH + c) * 2048 + g * 8 * 64;
  if (nsteps <= 0) {  // chunk fully past sequence end -> identity block
#pragma unroll
    for (int w = 0; w < 8; w++) {
      int c0 = g * 16 + 2 * w;
      unsigned v = (lane == c0 ? 0x3F80u : 0u) | (lane == c0 + 1 ? 0x3F800000u : 0u);
      Hc[w * 64 + lane] = v;
    }
    if (lane == 0) Eexp[(b * NCH + c) * 4 + g] = 0;
    return;
  }

  // A-frags: A = E^T, A[m=16mt+lm][k=16kt+4q+i] = exp(K[k*64+m])
  bf16x4 Af[4][4];
#pragma unroll
  for (int mt = 0; mt < 4; mt++)
#pragma unroll
    for (int kt = 0; kt < 4; kt++) {
      float v0 = __expf(K[(kt * 16 + rb + 0) * 64 + mt * 16 + lm]);
      float v1 = __expf(K[(kt * 16 + rb + 1) * 64 + mt * 16 + lm]);
      float v2 = __expf(K[(kt * 16 + rb + 2) * 64 + mt * 16 + lm]);
      float v3 = __expf(K[(kt * 16 + rb + 3) * 64 + mt * 16 + lm]);
      uint2 u; u.x = pkbf(v0, v1); u.y = pkbf(v2, v3);
      Af[mt][kt] = *(bf16x4*)&u;
    }

  // D_init = E^T: D[mt][r] = E^T[16mt+4q+r][16g+lm]
  f32x4 D[4];
#pragma unroll
  for (int mt = 0; mt < 4; mt++) {
    f32x4 d;
#pragma unroll
    for (int r = 0; r < 4; r++)
      d[r] = __expf(K[(g * 16 + lm) * 64 + mt * 16 + rb + r]);
    D[mt] = d;
  }

  // px ring: lane j produces exp(pot[t, j]) once; slot = t-t0 mod 4.
  float* ring = (float*)smem[wv];
  const float* Pj = pot + (size_t)b * TT * NN + lane;
#pragma unroll
  for (int k = 0; k < 3; k++) {  // slots 0..2 = px(t0..t0+2)
    int tt = t0 + k; tt = tt > TT - 1 ? TT - 1 : tt;
    ring[k * 64 + lane] = __expf(Pj[(size_t)tt * NN]);
  }
  int t3 = t0 + 3 > TT - 1 ? TT - 1 : t0 + 3;
  int t4 = t0 + 4 > TT - 1 ? TT - 1 : t0 + 4;
  float rawq0 = Pj[(size_t)t3 * NN];
  float rawq1 = Pj[(size_t)t4 * NN];

  int etot = 0;
  const int nit = nsteps - 1;
#pragma unroll 4
  for (int s = 0; s < nit; s++) {
    // px for this step, fresh from ring (broadcast b128 reads, offsets imm)
    f32x4 pxc[4];
#pragma unroll
    for (int kt = 0; kt < 4; kt++)
      pxc[kt] = *(const f32x4*)&ring[(s & 3) * 64 + kt * 16 + rb];
    if ((s & 7) == 7) {  // periodic exact power-of-2 renorm, folded into pxc
      float d00 = __int_as_float(__builtin_amdgcn_readfirstlane(__float_as_int(D[0][0])));
      int e = fexp(d00);
      float psc = ldexpf(1.0f, -e);
      etot += e;
#pragma unroll
      for (int kt = 0; kt < 4; kt++) pxc[kt] *= psc;
    }
    // B[kt] = bf16(pxc ⊙ D[kt]) — D layout == B layout
    bf16x4 Bf[4];
#pragma unroll
    for (int kt = 0; kt < 4; kt++) {
      f32x4 pr = D[kt] * pxc[kt];
      uint2 u;
      u.x = pkbf(pr[0], pr[1]);
      u.y = pkbf(pr[2], pr[3]);
      Bf[kt] = *(bf16x4*)&u;
    }
    // produce px(t+3) into ring; refill raw queue with raw(t+5)
    ring[((s + 3) & 3) * 64 + lane] = __expf(rawq0);
    rawq0 = rawq1;
    {
      int tn = t0 + s + 5; tn = tn > TT - 1 ? TT - 1 : tn;
      rawq1 = Pj[(size_t)tn * NN];
    }
    // D = A · B  (E^T · diag(p) · H)
#pragma unroll
    for (int mt = 0; mt < 4; mt++) {
      f32x4 acc = {0.f, 0.f, 0.f, 0.f};
#pragma unroll
      for (int kt = 0; kt < 4; kt++)
        acc = __builtin_amdgcn_mfma_f32_16x16x16bf16_1k(Af[mt][kt], Bf[kt], acc, 0, 0, 0);
      D[mt] = acc;
    }
  }

  // epilogue: H = diag(p_last)·D, renorm, transpose out via LDS (reuse ring mem)
  {
    f32x4 pxl[4];
#pragma unroll
    for (int kt = 0; kt < 4; kt++)
      pxl[kt] = *(const f32x4*)&ring[(nit & 3) * 64 + kt * 16 + rb];
    float hf = __int_as_float(
        __builtin_amdgcn_readfirstlane(__float_as_int(D[0][0] * pxl[0][0])));
    int ef = fexp(hf);
    float sc = ldexpf(1.0f, -ef);
    etot += ef;
    unsigned* sht = (unsigned*)smem[wv];
#pragma unroll
    for (int mt = 0; mt < 4; mt++) {
      f32x4 d = D[mt]; f32x4 pv = pxl[mt];
      int base = lm * 33 + mt * 8 + q * 2;
      sht[base]     = pkbf(d[0] * pv[0] * sc, d[1] * pv[1] * sc);
      sht[base + 1] = pkbf(d[2] * pv[2] * sc, d[3] * pv[3] * sc);
    }
#pragma unroll
    for (int w = 0; w < 8; w++) {
      unsigned short a0 = ((const unsigned short*)(sht + (2 * w) * 33 + (lane >> 1)))[lane & 1];
      unsigned short a1 = ((const unsigned short*)(sht + (2 * w + 1) * 33 + (lane >> 1)))[lane & 1];
      Hc[w * 64 + lane] = (unsigned)a0 | ((unsigned)a1 << 16);
    }
    if (lane == 0) Eexp[(b * NCH + c) * 4 + g] = etot;
  }
}

// ============================ PHASE 2 + REDUCE =============================
// 128 blocks x 64 threads (1 wave, batch b): 16 sequential chunk mat-vecs,
// 2-chunk register prefetch, LDS a-broadcast (same-wave ordering, no barriers).
__global__ __launch_bounds__(64, 4) void crf_phase2(
    const float* __restrict__ pot, const unsigned* __restrict__ Hg,
    const int* __restrict__ Eexp, const float* __restrict__ score,
    const float* __restrict__ wgt, float* __restrict__ accf,
    unsigned* __restrict__ cnt, float* __restrict__ out) {
  __shared__ __align__(16) float sha[64];
  const int j = threadIdx.x;
  const int b = blockIdx.x;

  float a = __expf(pot[(size_t)b * TT * NN + j]);
  sha[j] = a;
  int atot = 0;

  const unsigned* Hb = Hg + (size_t)b * NCH * 2048;
  unsigned bufA[32], bufB[32];
#pragma unroll
  for (int k = 0; k < 32; k++) bufA[k] = Hb[k * 64 + j];
#pragma unroll
  for (int k = 0; k < 32; k++) bufB[k] = Hb[2048 + k * 64 + j];

#pragma unroll
  for (int cc = 0; cc < NCH; cc += 2) {
#pragma unroll
    for (int half = 0; half < 2; half++) {
      const int c = cc + half;
      unsigned* cur = half ? bufB : bufA;
      // S_g[j] = sum over cols in group g of H[j][col] * a[col]
      float S[4] = {0.f, 0.f, 0.f, 0.f};
#pragma unroll
      for (int w4 = 0; w4 < 16; w4++) {
        f32x4 av = *(const f32x4*)&sha[w4 * 4];
        unsigned r0 = cur[2 * w4], r1 = cur[2 * w4 + 1];
        S[w4 >> 2] += __uint_as_float(r0 << 16) * av[0] +
                      __uint_as_float(r0 & 0xffff0000u) * av[1] +
                      __uint_as_float(r1 << 16) * av[2] +
                      __uint_as_float(r1 & 0xffff0000u) * av[3];
      }
      const int eb = b * 64 + c * 4;
      int e0 = Eexp[eb + 0], e1 = Eexp[eb + 1], e2 = Eexp[eb + 2], e3 = Eexp[eb + 3];
      int em = max(max(e0, e1), max(e2, e3));
      float Sc = ldexpf(S[0], e0 - em) + ldexpf(S[1], e1 - em) +
                 ldexpf(S[2], e2 - em) + ldexpf(S[3], e3 - em);
      int er = fexp(__int_as_float(
          __builtin_amdgcn_readfirstlane(__float_as_int(Sc))));
      a = ldexpf(Sc, -er);
      atot += em + er;
      sha[j] = a;  // same-wave DS ordering: visible to next chunk's reads
      // refill this buffer with chunk c+2
      if (c + 2 < NCH) {
        const unsigned* Hn = Hb + (size_t)(c + 2) * 2048;
#pragma unroll
        for (int k = 0; k < 32; k++) cur[k] = Hn[k * 64 + j];
      }
    }
  }

  float ssum = wave_sum64(a);
  if (j == 0) {
    float lognorm = __logf(ssum) + (float)atot * 0.69314718055994530942f;
    float loss = -(score[b] - lognorm) * wgt[b];
    atomicAdd(accf, loss * (1.0f / BB));
    __threadfence();
    unsigned old = atomicAdd(cnt, 1u);
    if (old == BB - 1) out[0] = atomicAdd(accf, 0.0f);
  }
}

// ===================== R1 fallback (ws too small) =====================
__global__ __launch_bounds__(64) void crf_main_fb(
    const float* __restrict__ pot, const int* __restrict__ tags,
    const int* __restrict__ seqlen, const float* __restrict__ K,
    float* __restrict__ ws) {
  __shared__ float sh[4096];
  const int lane = threadIdx.x;
  const int blk = blockIdx.x;
  if (blk < BB) {
    const int b = blk;
    const int L = seqlen[b];
    float Ec[64];
#pragma unroll
    for (int i = 0; i < 64; i++) Ec[i] = __expf(K[i * 64 + lane]);
    const float* pb = pot + (size_t)b * TT * NN + lane;
    float av = __expf(pb[0]);
    int etot = 0;
    sh[lane] = av;
    float pf[8];
#pragma unroll
    for (int k = 0; k < 8; k++) pf[k] = pb[(size_t)(1 + k) * 64];
    for (int t0 = 1; t0 < L; t0 += 8) {
#pragma unroll
      for (int k = 0; k < 8; k++) {
        const int t = t0 + k;
        const float pe = __expf(pf[k]);
        int tn = t + 8; tn = tn > (TT - 1) ? (TT - 1) : tn;
        pf[k] = pb[(size_t)tn * 64];
        const float4* arow = (const float4*)(sh + ((t - 1) & 1) * 64);
        float s[8];
#pragma unroll
        for (int qq = 0; qq < 8; qq++) s[qq] = 0.0f;
#pragma unroll
        for (int qq = 0; qq < 16; qq++) {
          float4 a4 = arow[qq];
          float pr = fmaf(a4.x, Ec[4 * qq + 0], fmaf(a4.y, Ec[4 * qq + 1],
                     fmaf(a4.z, Ec[4 * qq + 2], a4.w * Ec[4 * qq + 3])));
          s[qq & 7] += pr;
        }
        float S = ((s[0] + s[1]) + (s[2] + s[3])) + ((s[4] + s[5]) + (s[6] + s[7]));
        if (t < L) {
          av = S * pe;
          if ((t & 3) == 0) {
            float m0 = __shfl(av, 0, 64);
            int e = ((__float_as_int(m0) >> 23) & 0xff) - 126;
            av = ldexpf(av, -e);
            etot += e;
          }
        }
        sh[(t & 1) * 64 + lane] = av;
      }
    }
    float ssum = wave_sum64(av);
    if (lane == 0) ws[b] = __logf(ssum) + (float)etot * 0.69314718055994530942f;
  } else {
    const int b = blk - BB;
    const int L = seqlen[b];
    for (int i = lane; i < 4096; i += 64) sh[i] = K[i];
    __syncthreads();
    const int* tg = tags + b * TT;
    const float* pbase = pot + (size_t)b * TT * NN;
    float acc = 0.0f;
    for (int t = lane; t < TT; t += 64) {
      if (t < L) {
        int cc = tg[t];
        float u = pbase[(size_t)t * 64 + cc];
        float tr = 0.0f;
        if (t >= 1) tr = sh[tg[t - 1] * 64 + cc];
        acc += u + tr;
      }
    }
    acc = wave_sum64(acc);
    if (lane == 0) ws[BB + b] = acc;
  }
}

__global__ __launch_bounds__(128) void crf_combine_fb(
    const float* __restrict__ ws, const float* __restrict__ wgt,
    float* __restrict__ out) {
  const int i = threadIdx.x;
  float lv = -(ws[BB + i] - ws[i]) * wgt[i];
  lv = wave_sum64(lv);
  __shared__ float p[2];
  if ((i & 63) == 0) p[i >> 6] = lv;
  __syncthreads();
  if (i == 0) out[0] = (p[0] + p[1]) * (1.0f / 128.0f);
}

extern "C" void kernel_launch(void* const* d_in, const int* in_sizes, int n_in,
                              void* d_out, int out_size, void* d_ws, size_t ws_size,
                              hipStream_t stream) {
  const float* pot    = (const float*)d_in[0];
  const int*   tags   = (const int*)d_in[1];
  const int*   seqlen = (const int*)d_in[2];
  const float* K      = (const float*)d_in[3];
  const float* wgt    = (const float*)d_in[4];

  const size_t HG_DW = (size_t)BB * NCH * 2048;  // 16 MB of bf16-pair dwords
  const size_t NEXP  = (size_t)BB * NCH * 4;
  const size_t need  = (HG_DW + NEXP + BB + 2) * 4;

  if (ws_size >= need) {
    unsigned* Hg    = (unsigned*)d_ws;
    int* Eexp       = (int*)(Hg + HG_DW);
    float* score    = (float*)(Eexp + NEXP);
    float* accf     = score + BB;
    unsigned* cntp  = (unsigned*)(accf + 1);
    crf_phase1<<<32 + BB * NCH, 256, 0, stream>>>(pot, tags, seqlen, K, Hg, Eexp,
                                                  score, accf, cntp);
    crf_phase2<<<BB, 64, 0, stream>>>(pot, Hg, Eexp, score, wgt, accf, cntp,
                                      (float*)d_out);
  } else {
    float* ws = (float*)d_ws;
    crf_main_fb<<<256, 64, 0, stream>>>(pot, tags, seqlen, K, ws);
    crf_combine_fb<<<1, 128, 0, stream>>>(ws, wgt, (float*)d_out);
  }
}